// Round 8
// baseline (155.010 us; speedup 1.0000x reference)
//
#include <hip/hip_runtime.h>
#include <hip/hip_bf16.h>

#define B_ROWS 4096
#define DIN    768
#define DOUT   512
#define QDIM   64
#define H1C    32
#define H2C    64

typedef short  short8_t  __attribute__((ext_vector_type(8)));
typedef __bf16 bf16x8_t  __attribute__((ext_vector_type(8)));
typedef float  f32x4_t   __attribute__((ext_vector_type(4)));

__device__ __forceinline__ float bf16bits_to_f32(unsigned short u) {
  return __builtin_bit_cast(float, ((unsigned int)u) << 16);
}
__device__ __forceinline__ unsigned short f32_to_bf16bits(float f) {
  return __builtin_bit_cast(unsigned short, __float2bfloat16(f));
}
__device__ __forceinline__ float ldf(const void* p, int i, bool isb) {
  if (isb) return bf16bits_to_f32(((const unsigned short*)p)[i]);
  return ((const float*)p)[i];
}

// ---------- kernel 0: dtype detector (verified: picks fp32 here) ----------
__global__ __launch_bounds__(256) void k_detect(const unsigned int* __restrict__ xw,
                                                int* __restrict__ flag)
{
  const int t = threadIdx.x;
  int hit = 0;
  for (int i = t; i < 4096; i += 256) {
    const unsigned int e = (xw[i] >> 7) & 0xffu;
    if (e >= 118u && e <= 127u) hit++;
  }
#pragma unroll
  for (int off = 32; off >= 1; off >>= 1) hit += __shfl_down(hit, off);
  __shared__ int red[4];
  if ((t & 63) == 0) red[t >> 6] = hit;
  __syncthreads();
  if (t == 0) {
    const int total = red[0] + red[1] + red[2] + red[3];
    *flag = (total >= 2048) ? 1 : 0;
  }
}

// ---------- kernel 1: wp [768][512] -> wpT bf16 [512][768] (k-contiguous) ----------
__global__ __launch_bounds__(256) void k_conv_wpT(const void* __restrict__ wp,
                                                  unsigned short* __restrict__ wpT,
                                                  const int* __restrict__ flag)
{
  __shared__ unsigned short tile[32][33];
  const bool isb = (*flag != 0);
  const int n0 = blockIdx.x * 32, k0 = blockIdx.y * 32;
  const int tx = threadIdx.x, ty = threadIdx.y;
#pragma unroll
  for (int i = 0; i < 32; i += 8)
    tile[ty + i][tx] = f32_to_bf16bits(ldf(wp, (k0 + ty + i) * DOUT + n0 + tx, isb));
  __syncthreads();
#pragma unroll
  for (int i = 0; i < 32; i += 8)
    wpT[(size_t)(n0 + ty + i) * DIN + k0 + tx] = tile[tx][ty + i];
}

// ---------- kernel 2: FUSED gemm + KAN tail + LayerNorm, 16 rows/block ----------
// GEMM: M=16 (rows in LDS), each wave owns 128 N-cols; B-fragments loaded
// DIRECTLY from global wpT (short8/lane, L2-resident) -> no B LDS, no K-loop
// barriers. Epilogue parks x_proj in LDS (fp32), tail runs in-block.
__global__ __launch_bounds__(256) void k_fused(
    const void* __restrict__ x,              // [4096][768]
    const unsigned short* __restrict__ wpT,  // [512][768] bf16
    const void* __restrict__ bp,
    const void* __restrict__ wi1, const void* __restrict__ bi1,
    const void* __restrict__ wi2, const void* __restrict__ bi2,
    const void* __restrict__ wo1, const void* __restrict__ bo1,
    const void* __restrict__ wo2, const void* __restrict__ bo2,
    const void* __restrict__ gamma, const void* __restrict__ beta,
    void* __restrict__ out,
    const int* __restrict__ flag)
{
  // smem map (bytes):
  //  GEMM phase: As bf16[16][776]           [0, 24832)
  //  tail phase: sXp f32[16][516]           [0, 33024)   (overlays As after barrier)
  //  sWi2 [33024,41216) sS [41216,43264) sU [43264,47360) sT [47360,51456)
  //  sW1 51456 sB1 51584 sBi2 51712 sWo1 51968 sBo1 52224 sRed 52480 sStats 52992
  __shared__ alignas(16) char smem[53120];
  unsigned short* As  = (unsigned short*)smem;          // [16][776]
  float* sXp   = (float*)smem;                          // [16][516]
  float* sWi2  = (float*)(smem + 33024);
  float* sS    = (float*)(smem + 41216);                // [16][32]
  float* sU    = (float*)(smem + 43264);                // [16][64]
  float* sT    = (float*)(smem + 47360);                // [16][64]
  float* sW1   = (float*)(smem + 51456);
  float* sB1   = (float*)(smem + 51584);
  float* sBi2  = (float*)(smem + 51712);
  float* sWo1  = (float*)(smem + 51968);
  float* sBo1  = (float*)(smem + 52224);
  float* sRed  = (float*)(smem + 52480);                // [4][16][2]
  float* sStats= (float*)(smem + 52992);                // [16][2]

  const bool isb = (*flag != 0);
  const int t    = threadIdx.x;
  const int wave = t >> 6, lane = t & 63;
  const int lm   = lane & 15, quad = lane >> 4;
  const int b0   = blockIdx.x * 16;
  const int nb   = wave * 128;   // wave's exclusive N-range

  // ---- stage A: x rows b0..b0+15 -> As bf16 [16][776] (pad 8: bank-safe) ----
  {
    const int r = t >> 4, cb = (t & 15) * 8;
#pragma unroll
    for (int p = 0; p < 6; ++p) {
      const int c0 = p * 128 + cb;
      unsigned short a8[8];
      if (isb) {
        *(short8_t*)a8 = *(const short8_t*)
            ((const unsigned short*)x + (size_t)(b0 + r) * DIN + c0);
      } else {
        const float* px = (const float*)x + (size_t)(b0 + r) * DIN + c0;
        const float4 f0 = *(const float4*)px;
        const float4 f1 = *(const float4*)(px + 4);
        a8[0] = f32_to_bf16bits(f0.x); a8[1] = f32_to_bf16bits(f0.y);
        a8[2] = f32_to_bf16bits(f0.z); a8[3] = f32_to_bf16bits(f0.w);
        a8[4] = f32_to_bf16bits(f1.x); a8[5] = f32_to_bf16bits(f1.y);
        a8[6] = f32_to_bf16bits(f1.z); a8[7] = f32_to_bf16bits(f1.w);
      }
      *(short8_t*)&As[r * 776 + c0] = *(const short8_t*)a8;
    }
  }
  // ---- stage tail weights (region disjoint from As) ----
  for (int i = t; i < H1C * QDIM; i += 256) sWi2[i] = ldf(wi2, i, isb);
  if (t < 32)                   { sW1[t] = ldf(wi1, t, isb); sB1[t] = ldf(bi1, t, isb); }
  else if (t >= 64 && t < 128)  { const int j = t - 64;  sBi2[j] = ldf(bi2, j, isb); }
  else if (t >= 128 && t < 192) { const int j = t - 128; sWo1[j] = ldf(wo1, j, isb); }
  else if (t >= 192)            { const int j = t - 192; sBo1[j] = ldf(bo1, j, isb); }
  __syncthreads();

  // ---- K-loop: zero barriers; B straight from L2 ----
  f32x4_t acc[8] = {};
  const int qk = quad * 8;
  const unsigned short* wrow = wpT + (size_t)(nb + lm) * DIN + qk;
  for (int kt = 0; kt < DIN / 32; ++kt) {
    const short8_t av = *(const short8_t*)&As[lm * 776 + kt * 32 + qk];
    const bf16x8_t af = __builtin_bit_cast(bf16x8_t, av);
    short8_t bv[8];
#pragma unroll
    for (int nt = 0; nt < 8; ++nt)
      bv[nt] = *(const short8_t*)(wrow + (size_t)(nt * 16) * DIN + kt * 32);
#pragma unroll
    for (int nt = 0; nt < 8; ++nt)
      acc[nt] = __builtin_amdgcn_mfma_f32_16x16x32_bf16(
          af, __builtin_bit_cast(bf16x8_t, bv[nt]), acc[nt], 0, 0, 0);
  }
  __syncthreads();   // all waves done reading As before sXp overlays it

  // ---- epilogue: acc -> sXp fp32 [16][516]; C layout col=lm, row=quad*4+i ----
#pragma unroll
  for (int nt = 0; nt < 8; ++nt) {
    const int col = nb + nt * 16 + lm;
    const float bpv = ldf(bp, col, isb);
#pragma unroll
    for (int i = 0; i < 4; ++i)
      sXp[(quad * 4 + i) * 516 + col] = acc[nt][i] + bpv;
  }
  __syncthreads();

  // ---- phase S: S[r][h] = sum_d relu(xp[r][d]*wi1[h]+bi1[h]) ----
  {
    const int h = t & 31, rr = t >> 5;
    const float w = sW1[h], bb = sB1[h];
#pragma unroll
    for (int half = 0; half < 2; ++half) {
      const int r = rr + half * 8;
      const float* row = &sXp[r * 516];
      float a = 0.f;
      for (int d = 0; d < 512; d += 4) {
        const float4 v = *(const float4*)&row[d];
        a += fmaxf(fmaf(v.x, w, bb), 0.f);
        a += fmaxf(fmaf(v.y, w, bb), 0.f);
        a += fmaxf(fmaf(v.z, w, bb), 0.f);
        a += fmaxf(fmaf(v.w, w, bb), 0.f);
      }
      sS[r * H1C + h] = a;
    }
  }
  __syncthreads();

  // ---- phase u: u[r][q] = sum_h S[r][h]*wi2[h][q] + 512*bi2[q] ----
  for (int e = t; e < 16 * QDIM; e += 256) {
    const int r = e >> 6, q = e & 63;
    float a = 0.f;
#pragma unroll
    for (int h = 0; h < H1C; ++h) a = fmaf(sS[r * H1C + h], sWi2[h * QDIM + q], a);
    sU[e] = a + 512.f * sBi2[q];
  }
  __syncthreads();

  // ---- phase T: T[r][g] = sum_q relu(u[r][q]*wo1[g]+bo1[g]) ----
  for (int e = t; e < 16 * H2C; e += 256) {
    const int r = e >> 6, g = e & 63;
    const float w = sWo1[g], bb = sBo1[g];
    float a = 0.f;
#pragma unroll
    for (int q = 0; q < QDIM; ++q) a += fmaxf(fmaf(sU[r * QDIM + q], w, bb), 0.f);
    sT[e] = a;
  }
  __syncthreads();

  // ---- summed + LN: thread t owns cols d0=2t, d0+1 for all 16 rows ----
  const int d0 = 2 * t;
  float a0[16], a1[16];
#pragma unroll
  for (int r = 0; r < 16; ++r) { a0[r] = 0.f; a1[r] = 0.f; }

  for (int g = 0; g < H2C; ++g) {
    float w0, w1;
    if (isb) {
      const unsigned int pk = *(const unsigned int*)((const unsigned short*)wo2 + g * DOUT + d0);
      w0 = bf16bits_to_f32((unsigned short)(pk & 0xffffu));
      w1 = __builtin_bit_cast(float, pk & 0xffff0000u);
    } else {
      const float2 f = *(const float2*)((const float*)wo2 + g * DOUT + d0);
      w0 = f.x; w1 = f.y;
    }
#pragma unroll
    for (int r = 0; r < 16; ++r) {
      const float tv = sT[r * H2C + g];
      a0[r] = fmaf(tv, w0, a0[r]);
      a1[r] = fmaf(tv, w1, a1[r]);
    }
  }
  const float bb0 = 64.f * ldf(bo2, d0, isb);
  const float bb1 = 64.f * ldf(bo2, d0 + 1, isb);
#pragma unroll
  for (int r = 0; r < 16; ++r) { a0[r] += bb0; a1[r] += bb1; }

  float pr[16], prs[16];
#pragma unroll
  for (int r = 0; r < 16; ++r) {
    pr[r]  = a0[r] + a1[r];
    prs[r] = a0[r] * a0[r] + a1[r] * a1[r];
  }
#pragma unroll
  for (int off = 1; off < 64; off <<= 1) {
#pragma unroll
    for (int r = 0; r < 16; ++r) {
      pr[r]  += __shfl_xor(pr[r],  off);
      prs[r] += __shfl_xor(prs[r], off);
    }
  }
  const int ln = t & 63;
  if (ln == 0) {
#pragma unroll
    for (int r = 0; r < 16; ++r) {
      sRed[(wave * 16 + r) * 2 + 0] = pr[r];
      sRed[(wave * 16 + r) * 2 + 1] = prs[r];
    }
  }
  __syncthreads();
  if (t < 16) {
    float sm = 0.f, sq = 0.f;
#pragma unroll
    for (int w = 0; w < 4; ++w) {
      sm += sRed[(w * 16 + t) * 2 + 0];
      sq += sRed[(w * 16 + t) * 2 + 1];
    }
    const float mu  = sm * (1.f / 512.f);
    const float var = fmaxf(sq * (1.f / 512.f) - mu * mu, 0.f);
    sStats[t * 2 + 0] = mu;
    sStats[t * 2 + 1] = rsqrtf(var + 1e-5f);
  }
  __syncthreads();

  const float g0 = ldf(gamma, d0, isb),  g1 = ldf(gamma, d0 + 1, isb);
  const float be0 = ldf(beta, d0, isb),  be1 = ldf(beta, d0 + 1, isb);
#pragma unroll
  for (int r = 0; r < 16; ++r) {
    const float mu = sStats[r * 2 + 0], rstd = sStats[r * 2 + 1];
    const float o0 = (a0[r] - mu) * rstd * g0 + be0;
    const float o1 = (a1[r] - mu) * rstd * g1 + be1;
    if (isb) {
      unsigned short* op = (unsigned short*)out + (size_t)(b0 + r) * DOUT + d0;
      op[0] = f32_to_bf16bits(o0);
      op[1] = f32_to_bf16bits(o1);
    } else {
      float* op = (float*)out + (size_t)(b0 + r) * DOUT + d0;
      op[0] = o0;
      op[1] = o1;
    }
  }
}

extern "C" void kernel_launch(void* const* d_in, const int* in_sizes, int n_in,
                              void* d_out, int out_size, void* d_ws, size_t ws_size,
                              hipStream_t stream) {
  const void* x     = d_in[0];
  const void* wp    = d_in[1];
  const void* bp    = d_in[2];
  const void* wi1   = d_in[3];
  const void* bi1   = d_in[4];
  const void* wi2   = d_in[5];
  const void* bi2   = d_in[6];
  const void* wo1   = d_in[7];
  const void* bo1   = d_in[8];
  const void* wo2   = d_in[9];
  const void* bo2   = d_in[10];
  const void* gamma = d_in[11];
  const void* beta  = d_in[12];

  int* flag = (int*)d_ws;                                      // 4 B
  unsigned short* wpT = (unsigned short*)((char*)d_ws + 4096); // 768 KB bf16

  k_detect<<<1, 256, 0, stream>>>((const unsigned int*)x, flag);
  k_conv_wpT<<<dim3(DOUT / 32, DIN / 32), dim3(32, 8), 0, stream>>>(wp, wpT, flag);
  k_fused<<<B_ROWS / 16, 256, 0, stream>>>(x, wpT, bp, wi1, bi1, wi2, bi2,
                                           wo1, bo1, wo2, bo2, gamma, beta,
                                           d_out, flag);
}

// Round 9
// 134.504 us; speedup vs baseline: 1.1525x; 1.1525x over previous
//
#include <hip/hip_runtime.h>
#include <hip/hip_bf16.h>

#define B_ROWS 4096
#define DIN    768
#define DOUT   512
#define QDIM   64
#define H1C    32
#define H2C    64

// canonical fp32 weight block offsets (floats)
#define W_BP    0
#define W_WI1   512
#define W_BI1   544
#define W_WI2   576
#define W_BI2   2624
#define W_WO1   2688
#define W_BO1   2752
#define W_WO2   2816
#define W_BO2   35584
#define W_GAM   36096
#define W_BET   36608
#define W_TOT   37120

typedef short  short8_t  __attribute__((ext_vector_type(8)));
typedef __bf16 bf16x8_t  __attribute__((ext_vector_type(8)));
typedef float  f32x4_t   __attribute__((ext_vector_type(4)));

__device__ __forceinline__ float bf16bits_to_f32(unsigned short u) {
  return __builtin_bit_cast(float, ((unsigned int)u) << 16);
}
__device__ __forceinline__ unsigned short f32_to_bf16bits(float f) {
  return __builtin_bit_cast(unsigned short, __float2bfloat16(f));
}
__device__ __forceinline__ float ldf(const void* p, int i, bool isb) {
  if (isb) return bf16bits_to_f32(((const unsigned short*)p)[i]);
  return ((const float*)p)[i];
}
// per-wave dtype detect from x's first 64 words (verified: picks fp32 here)
__device__ __forceinline__ bool detect_bf16(const unsigned int* xw, int t) {
  const unsigned int w = xw[t & 63];
  const unsigned int e = (w >> 7) & 0xffu;
  const bool hit = (e >= 118u && e <= 127u);   // bf16 N(0,1): ~95%, fp32 mantissa: ~4%
  return __popcll(__ballot(hit)) >= 40;
}

// ---------- kernel 1: canonicalize x -> xb bf16, wp -> wpT bf16, weights -> wW fp32 ----------
__global__ __launch_bounds__(256) void k_prep(
    const void* __restrict__ x, const void* __restrict__ wp,
    const void* __restrict__ bp,
    const void* __restrict__ wi1, const void* __restrict__ bi1,
    const void* __restrict__ wi2, const void* __restrict__ bi2,
    const void* __restrict__ wo1, const void* __restrict__ bo1,
    const void* __restrict__ wo2, const void* __restrict__ bo2,
    const void* __restrict__ gamma, const void* __restrict__ beta,
    unsigned short* __restrict__ xb,    // [4096][768] bf16
    unsigned short* __restrict__ wpT,   // [512][768]  bf16
    float* __restrict__ wW)             // [37120] fp32
{
  const int t = threadIdx.x, b = blockIdx.x;
  const bool isb = detect_bf16((const unsigned int*)x, t);

  if (b < 384) {
    // x conversion: 8192 elems/block
    const int base = b * 8192 + t * 4;
#pragma unroll
    for (int j = 0; j < 8; ++j) {
      const int idx = base + j * 1024;
      if (isb) {
        *(uint2*)&xb[idx] = *(const uint2*)((const unsigned short*)x + idx);
      } else {
        const float4 f = *(const float4*)((const float*)x + idx);
        ushort4 o;
        o.x = f32_to_bf16bits(f.x); o.y = f32_to_bf16bits(f.y);
        o.z = f32_to_bf16bits(f.z); o.w = f32_to_bf16bits(f.w);
        *(ushort4*)&xb[idx] = o;
      }
    }
  } else if (b < 768) {
    // wp [768][512] -> wpT [512][768], 32x32 tiles (16 n-tiles x 24 k-tiles)
    __shared__ unsigned short tile[32][33];
    const int tb = b - 384;
    const int n0 = (tb & 15) * 32, k0 = (tb >> 4) * 32;
    const int tx = t & 31, ty = t >> 5;   // 32 x 8
#pragma unroll
    for (int i = 0; i < 32; i += 8)
      tile[ty + i][tx] = f32_to_bf16bits(ldf(wp, (k0 + ty + i) * DOUT + n0 + tx, isb));
    __syncthreads();
#pragma unroll
    for (int i = 0; i < 32; i += 8)
      wpT[(size_t)(n0 + ty + i) * DIN + k0 + tx] = tile[tx][ty + i];
  } else {
    // small weights -> canonical fp32 block
    for (int e = (b - 768) * 256 + t; e < W_TOT; e += 8 * 256) {
      float v;
      if      (e < W_WI1) v = ldf(bp,    e - W_BP,  isb);
      else if (e < W_BI1) v = ldf(wi1,   e - W_WI1, isb);
      else if (e < W_WI2) v = ldf(bi1,   e - W_BI1, isb);
      else if (e < W_BI2) v = ldf(wi2,   e - W_WI2, isb);
      else if (e < W_WO1) v = ldf(bi2,   e - W_BI2, isb);
      else if (e < W_BO1) v = ldf(wo1,   e - W_WO1, isb);
      else if (e < W_WO2) v = ldf(bo1,   e - W_BO1, isb);
      else if (e < W_BO2) v = ldf(wo2,   e - W_WO2, isb);
      else if (e < W_GAM) v = ldf(bo2,   e - W_BO2, isb);
      else if (e < W_BET) v = ldf(gamma, e - W_GAM, isb);
      else                v = ldf(beta,  e - W_BET, isb);
      wW[e] = v;
    }
  }
}

// ---------- kernel 2: fused GEMM + KAN tail + LN, 16 rows/block, 512 threads ----------
// 8 waves, each owns 64 N-cols (4 MFMA chains). B direct from L2 with explicit
// 1-iter register prefetch. A staged once in LDS (no K-loop barriers).
__global__ __launch_bounds__(512, 2) void k_main(
    const unsigned int* __restrict__ xw,     // x as words (for dtype detect)
    const unsigned short* __restrict__ xb,   // [4096][768] bf16
    const unsigned short* __restrict__ wpT,  // [512][768]  bf16
    const float* __restrict__ wW,            // canonical fp32 weights
    void* __restrict__ out)
{
  // LDS: As bf16[16][776] (24.8KB) overlaid by sXp f32[16][516] (33KB)
  __shared__ alignas(16) char smem[44416];
  unsigned short* As   = (unsigned short*)smem;
  float* sXp   = (float*)smem;
  float* sS    = (float*)(smem + 33024);   // [16][32]
  float* sU    = (float*)(smem + 35072);   // [16][64]
  float* sT    = (float*)(smem + 39168);   // [16][64]
  float* sRed  = (float*)(smem + 43264);   // [8][16][2]
  float* sStats= (float*)(smem + 44288);   // [16][2]

  const int t    = threadIdx.x;
  const int wv   = t >> 6, lane = t & 63;
  const int lm   = lane & 15, quad = lane >> 4;
  const int b0   = blockIdx.x * 16;
  const bool isb = detect_bf16(xw, t);

  // ---- stage A rows b0..b0+15 (bf16 from xb): 16 rows x 96 chunks of 8 ----
  for (int e = t; e < 16 * 96; e += 512) {
    const int r = e / 96, c = (e % 96) * 8;
    *(short8_t*)&As[r * 776 + c] =
        *(const short8_t*)(xb + (size_t)(b0 + r) * DIN + c);
  }
  __syncthreads();

  // ---- K-loop: A from LDS, B from L2 with register prefetch; no barriers ----
  f32x4_t acc[4] = {};
  const unsigned short* wb0 = wpT + (size_t)(wv * 64 + lm) * DIN + quad * 8;
  short8_t bcur[4], bnxt[4];
#pragma unroll
  for (int nt = 0; nt < 4; ++nt)
    bcur[nt] = *(const short8_t*)(wb0 + nt * 16 * DIN);
  for (int kt = 0; kt < 24; ++kt) {
    const int kn = (kt < 23) ? kt + 1 : 23;
#pragma unroll
    for (int nt = 0; nt < 4; ++nt)
      bnxt[nt] = *(const short8_t*)(wb0 + nt * 16 * DIN + kn * 32);
    const short8_t av = *(const short8_t*)&As[lm * 776 + kt * 32 + quad * 8];
    const bf16x8_t af = __builtin_bit_cast(bf16x8_t, av);
#pragma unroll
    for (int nt = 0; nt < 4; ++nt)
      acc[nt] = __builtin_amdgcn_mfma_f32_16x16x32_bf16(
          af, __builtin_bit_cast(bf16x8_t, bcur[nt]), acc[nt], 0, 0, 0);
#pragma unroll
    for (int nt = 0; nt < 4; ++nt) bcur[nt] = bnxt[nt];
  }
  __syncthreads();   // all As reads done before sXp overlays

  // ---- epilogue: C layout col=lm, row=quad*4+i (verified R7) ----
#pragma unroll
  for (int nt = 0; nt < 4; ++nt) {
    const int col = wv * 64 + nt * 16 + lm;
    const float bpv = wW[W_BP + col];
#pragma unroll
    for (int i = 0; i < 4; ++i)
      sXp[(quad * 4 + i) * 516 + col] = acc[nt][i] + bpv;
  }
  __syncthreads();

  // ---- phase S: S[r][h] = sum_d relu(xp[r][d]*wi1[h]+bi1[h]); 512 thr = 16r x 32h ----
  {
    const int h = t & 31, r = t >> 5;
    const float w = wW[W_WI1 + h], bb = wW[W_BI1 + h];
    const float* row = &sXp[r * 516];
    float a = 0.f;
    for (int d = 0; d < 512; d += 4) {
      const float4 v = *(const float4*)&row[d];
      a += fmaxf(fmaf(v.x, w, bb), 0.f);
      a += fmaxf(fmaf(v.y, w, bb), 0.f);
      a += fmaxf(fmaf(v.z, w, bb), 0.f);
      a += fmaxf(fmaf(v.w, w, bb), 0.f);
    }
    sS[r * H1C + h] = a;
  }
  __syncthreads();

  // ---- phase u: u[r][q] = sum_h S[r][h]*wi2[h][q] + 512*bi2[q] ----
  for (int e = t; e < 16 * QDIM; e += 512) {
    const int r = e >> 6, q = e & 63;
    float a = 0.f;
#pragma unroll
    for (int h = 0; h < H1C; ++h)
      a = fmaf(sS[r * H1C + h], wW[W_WI2 + h * QDIM + q], a);
    sU[e] = a + 512.f * wW[W_BI2 + q];
  }
  __syncthreads();

  // ---- phase T: T[r][g] = sum_q relu(u[r][q]*wo1[g]+bo1[g]) ----
  for (int e = t; e < 16 * H2C; e += 512) {
    const int r = e >> 6, g = e & 63;
    const float w = wW[W_WO1 + g], bb = wW[W_BO1 + g];
    float a = 0.f;
#pragma unroll
    for (int q = 0; q < QDIM; ++q)
      a += fmaxf(fmaf(sU[r * QDIM + q], w, bb), 0.f);
    sT[e] = a;
  }
  __syncthreads();

  // ---- summed + LN: thread t owns col t for all 16 rows ----
  const int d0 = t;
  float a[16];
#pragma unroll
  for (int r = 0; r < 16; ++r) a[r] = 0.f;
  for (int g = 0; g < H2C; ++g) {
    const float w = wW[W_WO2 + g * DOUT + d0];   // coalesced, L2/L1
#pragma unroll
    for (int r = 0; r < 16; ++r)
      a[r] = fmaf(sT[r * H2C + g], w, a[r]);
  }
  const float bo2v = 64.f * wW[W_BO2 + d0];
#pragma unroll
  for (int r = 0; r < 16; ++r) a[r] += bo2v;

  float pr[16], prs[16];
#pragma unroll
  for (int r = 0; r < 16; ++r) { pr[r] = a[r]; prs[r] = a[r] * a[r]; }
#pragma unroll
  for (int off = 1; off < 64; off <<= 1) {
#pragma unroll
    for (int r = 0; r < 16; ++r) {
      pr[r]  += __shfl_xor(pr[r],  off);
      prs[r] += __shfl_xor(prs[r], off);
    }
  }
  if (lane == 0) {
#pragma unroll
    for (int r = 0; r < 16; ++r) {
      sRed[(wv * 16 + r) * 2 + 0] = pr[r];
      sRed[(wv * 16 + r) * 2 + 1] = prs[r];
    }
  }
  __syncthreads();
  if (t < 16) {
    float sm = 0.f, sq = 0.f;
#pragma unroll
    for (int w = 0; w < 8; ++w) {
      sm += sRed[(w * 16 + t) * 2 + 0];
      sq += sRed[(w * 16 + t) * 2 + 1];
    }
    const float mu  = sm * (1.f / 512.f);
    const float var = fmaxf(sq * (1.f / 512.f) - mu * mu, 0.f);
    sStats[t * 2 + 0] = mu;
    sStats[t * 2 + 1] = rsqrtf(var + 1e-5f);
  }
  __syncthreads();

  const float gm = wW[W_GAM + d0], bt = wW[W_BET + d0];
#pragma unroll
  for (int r = 0; r < 16; ++r) {
    const float o = (a[r] - sStats[r * 2 + 0]) * sStats[r * 2 + 1] * gm + bt;
    if (isb)
      ((unsigned short*)out)[(size_t)(b0 + r) * DOUT + d0] = f32_to_bf16bits(o);
    else
      ((float*)out)[(size_t)(b0 + r) * DOUT + d0] = o;
  }
}

extern "C" void kernel_launch(void* const* d_in, const int* in_sizes, int n_in,
                              void* d_out, int out_size, void* d_ws, size_t ws_size,
                              hipStream_t stream) {
  const void* x     = d_in[0];
  const void* wp    = d_in[1];

  char* ws = (char*)d_ws;
  unsigned short* xb  = (unsigned short*)ws;                       // 6 MB
  unsigned short* wpT = (unsigned short*)(ws + 6291456);           // 768 KB
  float*          wW  = (float*)(ws + 7077888);                    // 145 KB
  // total ws use ~7.23 MB (<= 11 MB proven in R3)

  k_prep<<<776, 256, 0, stream>>>(x, wp, d_in[2], d_in[3], d_in[4], d_in[5],
                                  d_in[6], d_in[7], d_in[8], d_in[9], d_in[10],
                                  d_in[11], d_in[12], xb, wpT, wW);
  k_main<<<B_ROWS / 16, 512, 0, stream>>>((const unsigned int*)x, xb, wpT, wW, d_out);
}